// Round 9
// baseline (412.122 us; speedup 1.0000x reference)
//
#include <hip/hip_runtime.h>
#include <hip/hip_bf16.h>
#include <cmath>
#include <cstdint>

#define T 2048
#define H 1024
#define NH 16
#define NKV 4
#define DH 64
#define NE 8
#define FF 1024
#define QKVN ((NH + 2 * NKV) * DH) /* 1536 */
#define EPS 1e-5f
#define ATTN_SCALE 0.125f
#define LOG2E 1.44269504f
#define MBOUND 12.0f  /* > 64*0.125*log2e = 11.54; scores can't exceed it (rms-normed q,k) */
#define ASPLIT 4      /* KV split factor: static-max softmax -> partials are additive */

typedef short bf16x8 __attribute__((ext_vector_type(8)));
typedef float floatx4 __attribute__((ext_vector_type(4)));

__device__ __forceinline__ void gload16(const void* g, void* l) {
  __builtin_amdgcn_global_load_lds((const __attribute__((address_space(1))) void*)g,
                                   (__attribute__((address_space(3))) void*)l, 16, 0, 0);
}

// ---------------- rmsnorm rows of 1024 -> bf16 ----------------
__global__ __launch_bounds__(256) void rmsnorm1024(const float* __restrict__ x,
                                                   const float* __restrict__ w,
                                                   __hip_bfloat16* __restrict__ yb) {
  int row = blockIdx.x;
  const float4* x4 = (const float4*)(x + (size_t)row * H);
  float4 v = x4[threadIdx.x];
  float s = v.x * v.x + v.y * v.y + v.z * v.z + v.w * v.w;
  #pragma unroll
  for (int o = 32; o; o >>= 1) s += __shfl_down(s, o, 64);
  __shared__ float red[4];
  if ((threadIdx.x & 63) == 0) red[threadIdx.x >> 6] = s;
  __syncthreads();
  s = red[0] + red[1] + red[2] + red[3];
  float inv = rsqrtf(s * (1.0f / (float)H) + EPS);
  float4 wv = ((const float4*)w)[threadIdx.x];
  __hip_bfloat16* yp = yb + (size_t)row * H + threadIdx.x * 4;
  yp[0] = __float2bfloat16(v.x * inv * wv.x);
  yp[1] = __float2bfloat16(v.y * inv * wv.y);
  yp[2] = __float2bfloat16(v.z * inv * wv.z);
  yp[3] = __float2bfloat16(v.w * inv * wv.w);
}

// -- fused: h2b = bf16(rmsnorm(resid)*w); router top-1 + sigmoid gate --
// (h2 fp32 buffer eliminated; counts zeroed earlier by attn_combine)
__global__ __launch_bounds__(256) void rms_router(const float* __restrict__ x,
                                                  const float* __restrict__ w,
                                                  const float* __restrict__ rw,
                                                  __hip_bfloat16* __restrict__ yb,
                                                  int* __restrict__ idx,
                                                  float* __restrict__ gate,
                                                  int* __restrict__ counts) {
  int row = blockIdx.x;
  float4 v = ((const float4*)(x + (size_t)row * H))[threadIdx.x];
  float s = v.x * v.x + v.y * v.y + v.z * v.z + v.w * v.w;
  #pragma unroll
  for (int o = 32; o; o >>= 1) s += __shfl_down(s, o, 64);
  __shared__ float red[4];
  if ((threadIdx.x & 63) == 0) red[threadIdx.x >> 6] = s;
  __syncthreads();
  s = red[0] + red[1] + red[2] + red[3];
  float inv = rsqrtf(s * (1.0f / (float)H) + EPS);
  float4 wv = ((const float4*)w)[threadIdx.x];
  float o0 = v.x * inv * wv.x, o1 = v.y * inv * wv.y, o2 = v.z * inv * wv.z, o3 = v.w * inv * wv.w;
  __hip_bfloat16* yp = yb + (size_t)row * H + threadIdx.x * 4;
  yp[0] = __float2bfloat16(o0);
  yp[1] = __float2bfloat16(o1);
  yp[2] = __float2bfloat16(o2);
  yp[3] = __float2bfloat16(o3);
  // router: this thread's 4 columns dot rw[c][e]
  const float* r0 = rw + (size_t)threadIdx.x * 4 * NE;
  float acc[NE];
  float4 a0 = *(const float4*)(r0 + 0), a1 = *(const float4*)(r0 + 4);
  float4 b0 = *(const float4*)(r0 + NE), b1 = *(const float4*)(r0 + NE + 4);
  float4 c0 = *(const float4*)(r0 + 2 * NE), c1 = *(const float4*)(r0 + 2 * NE + 4);
  float4 d0 = *(const float4*)(r0 + 3 * NE), d1 = *(const float4*)(r0 + 3 * NE + 4);
  acc[0] = o0 * a0.x + o1 * b0.x + o2 * c0.x + o3 * d0.x;
  acc[1] = o0 * a0.y + o1 * b0.y + o2 * c0.y + o3 * d0.y;
  acc[2] = o0 * a0.z + o1 * b0.z + o2 * c0.z + o3 * d0.z;
  acc[3] = o0 * a0.w + o1 * b0.w + o2 * c0.w + o3 * d0.w;
  acc[4] = o0 * a1.x + o1 * b1.x + o2 * c1.x + o3 * d1.x;
  acc[5] = o0 * a1.y + o1 * b1.y + o2 * c1.y + o3 * d1.y;
  acc[6] = o0 * a1.z + o1 * b1.z + o2 * c1.z + o3 * d1.z;
  acc[7] = o0 * a1.w + o1 * b1.w + o2 * c1.w + o3 * d1.w;
  #pragma unroll
  for (int off = 32; off; off >>= 1)
    #pragma unroll
    for (int e2 = 0; e2 < NE; e2++) acc[e2] += __shfl_down(acc[e2], off, 64);
  __shared__ float redr[4][NE];
  if ((threadIdx.x & 63) == 0)
    #pragma unroll
    for (int e2 = 0; e2 < NE; e2++) redr[threadIdx.x >> 6][e2] = acc[e2];
  __syncthreads();
  if (threadIdx.x == 0) {
    int best = 0;
    float bv = -3.4e38f;
    #pragma unroll
    for (int e2 = 0; e2 < NE; e2++) {
      float l = redr[0][e2] + redr[1][e2] + redr[2][e2] + redr[3][e2];
      if (l > bv) { bv = l; best = e2; }
    }
    idx[row] = best;
    gate[row] = 1.f / (1.f + expf(-bv));
    atomicAdd(&counts[best], 1);
  }
}

// -- fp32 [R][C] -> bf16 [C][R]; dual source-set batched (z<nz1: E/S, z>=nz1: E2/S2) --
__global__ __launch_bounds__(256) void tcast9(const float* __restrict__ srcE,
                                              const float* __restrict__ srcS,
                                              const float* __restrict__ srcE2,
                                              const float* __restrict__ srcS2,
                                              __hip_bfloat16* __restrict__ dst, int R, int C,
                                              long long srcStride, long long dstStride,
                                              long long sBatch, long long dBatch,
                                              long long d2Off, int nz1) {
  int z = blockIdx.z;
  const float* src;
  if (z < nz1) {
    src = (srcS && z == nz1 - 1) ? srcS : srcE + (long long)z * sBatch;
    dst += (long long)z * dBatch;
  } else {
    int z2 = z - nz1;
    src = (srcS2 && z2 == nz1 - 1) ? srcS2 : srcE2 + (long long)z2 * sBatch;
    dst += d2Off + (long long)z2 * dBatch;
  }
  int c0 = blockIdx.x * 64, r0 = blockIdx.y * 32;
  __shared__ float tile[32][65];
  int tid = threadIdx.x;
  int lr = tid >> 4;
  int lc = (tid & 15) * 4;
  #pragma unroll
  for (int it = 0; it < 2; it++) {
    float4 v = *(const float4*)(src + (long long)(r0 + lr + it * 16) * srcStride + c0 + lc);
    tile[lr + it * 16][lc + 0] = v.x;
    tile[lr + it * 16][lc + 1] = v.y;
    tile[lr + it * 16][lc + 2] = v.z;
    tile[lr + it * 16][lc + 3] = v.w;
  }
  __syncthreads();
  int oc = tid >> 2;
  int rr = (tid & 3) * 8;
  short ov[8];
  #pragma unroll
  for (int i = 0; i < 8; i++) {
    __hip_bfloat16 b = __float2bfloat16(tile[rr + i][oc]);
    ov[i] = *(short*)&b;
  }
  *(bf16x8*)((short*)dst + (long long)(c0 + oc) * dstStride + r0 + rr) = *(bf16x8*)ov;
}

// ------------- bf16 MFMA GEMM, 128x64 tile, BK=64, XOR-swizzled LDS -------------
// 2-phase: double-buffered LDS, prefetch next K-tile before computing current.
// C[M,N] = A[M,K] * Bt[N,K]^T ; last z slot (if A2) uses A2/full rows/Cout2.
// permA: row indirection for A; gatev: epilogue row scale (linear domain);
// addC: fp32 addend; scatterPerm: if set, C row = scatterPerm[gm], ACCUMULATE (+=).
__global__ __launch_bounds__(256) void gemm_bf16(const __hip_bfloat16* __restrict__ A,
                                                 const __hip_bfloat16* __restrict__ A2,
                                                 const __hip_bfloat16* __restrict__ Bt,
                                                 void* __restrict__ Cout, void* __restrict__ Cout2,
                                                 int M, int N, int K, int out_bf16,
                                                 const int* __restrict__ row_offs,
                                                 long long strideB,
                                                 const int* __restrict__ permA,
                                                 const float* __restrict__ gatev,
                                                 const float* __restrict__ addC,
                                                 const int* __restrict__ scatterPerm) {
  int e = blockIdx.z;
  bool sh = (A2 != nullptr && e == (int)gridDim.z - 1);
  int rbeg = 0, rend = M;
  const __hip_bfloat16* Ap = A;
  void* Cp = Cout;
  const int* pA = permA;
  if (sh) {
    Ap = A2; Cp = Cout2; pA = nullptr;
  } else if (row_offs) {
    rbeg = row_offs[e]; rend = row_offs[e + 1];
  }
  long long m0 = rbeg + (long long)blockIdx.y * 128;
  if (m0 >= rend) return;
  long long n0 = (long long)blockIdx.x * 64;
  const __hip_bfloat16* Bp = Bt + (long long)e * strideB;

  __shared__ unsigned short As[2][128 * 64];
  __shared__ unsigned short Bs[2][64 * 64];

  int tid = threadIdx.x;
  int lane = tid & 63, w = tid >> 6;
  int wr = (w >> 1) * 64, wc = (w & 1) * 32;
  int qd = lane >> 4, ln16 = lane & 15;
  int l7 = ln16 & 7;

  floatx4 acc[4][2];
  floatx4 zero = {0.f, 0.f, 0.f, 0.f};
  #pragma unroll
  for (int i = 0; i < 4; i++)
    #pragma unroll
    for (int j = 0; j < 2; j++) acc[i][j] = zero;

  int rowA[4], kcA[4];
  const unsigned short* Arow[4];
  const unsigned short* Brow[2];
  #pragma unroll
  for (int it = 0; it < 4; it++) {
    int chunk = tid + it * 256;
    rowA[it] = chunk >> 3;
    kcA[it] = ((chunk & 7) ^ (rowA[it] & 7)) * 8;
    long long ra = m0 + rowA[it];
    if (ra >= rend) ra = rend - 1;
    long long tok = pA ? (long long)pA[ra] : ra;
    Arow[it] = (const unsigned short*)Ap + tok * K;
  }
  #pragma unroll
  for (int it = 0; it < 2; it++)
    Brow[it] = (const unsigned short*)Bp + (n0 + rowA[it]) * K;

  // prologue: stage k0=0 into buffer 0
  #pragma unroll
  for (int it = 0; it < 4; it++)
    gload16(Arow[it] + kcA[it], As[0] + (tid + it * 256) * 8);
  #pragma unroll
  for (int it = 0; it < 2; it++)
    gload16(Brow[it] + kcA[it], Bs[0] + (tid + it * 256) * 8);
  __syncthreads();

  int cur = 0;
  for (int k0 = 0; k0 < K; k0 += 64) {
    int kn = k0 + 64;
    if (kn < K) {
      #pragma unroll
      for (int it = 0; it < 4; it++)
        gload16(Arow[it] + kn + kcA[it], As[cur ^ 1] + (tid + it * 256) * 8);
      #pragma unroll
      for (int it = 0; it < 2; it++)
        gload16(Brow[it] + kn + kcA[it], Bs[cur ^ 1] + (tid + it * 256) * 8);
    }
    const unsigned short* Ac = As[cur];
    const unsigned short* Bc = Bs[cur];
    #pragma unroll
    for (int s = 0; s < 2; s++) {
      bf16x8 af[4], bfr[2];
      #pragma unroll
      for (int i = 0; i < 4; i++) {
        int row = wr + i * 16 + ln16;
        af[i] = *(const bf16x8*)(Ac + row * 64 + (((s * 4 + qd) ^ l7) * 8));
      }
      #pragma unroll
      for (int j = 0; j < 2; j++) {
        int row = wc + j * 16 + ln16;
        bfr[j] = *(const bf16x8*)(Bc + row * 64 + (((s * 4 + qd) ^ l7) * 8));
      }
      #pragma unroll
      for (int i = 0; i < 4; i++)
        #pragma unroll
        for (int j = 0; j < 2; j++)
          acc[i][j] = __builtin_amdgcn_mfma_f32_16x16x32_bf16(af[i], bfr[j], acc[i][j], 0, 0, 0);
    }
    __syncthreads();
    cur ^= 1;
  }

  #pragma unroll
  for (int i = 0; i < 4; i++) {
    #pragma unroll
    for (int r = 0; r < 4; r++) {
      long long gm = m0 + wr + i * 16 + qd * 4 + r;
      if (gm < rend) {
        float gsc = 1.0f;
        if (pA && gatev) gsc = gatev[pA[gm]];
        #pragma unroll
        for (int j = 0; j < 2; j++) {
          long long gn = n0 + wc + j * 16 + ln16;
          float v = acc[i][j][r] * gsc;
          if (addC) v += addC[gm * N + gn];
          if (scatterPerm) {
            float* op = (float*)Cp + (size_t)scatterPerm[gm] * N + gn;
            *op += v;
          } else if (out_bf16)
            ((__hip_bfloat16*)Cp)[gm * N + gn] = __float2bfloat16(v);
          else
            ((float*)Cp)[gm * N + gn] = v;
        }
      }
    }
  }
}

// ---- specialized qkv GEMM: fused RoPE + per-head rmsnorm + Qb/Kb/V^T epilogue ----
// grid (QKVN/64 = 24, T/128). Wave w owns rows [w*32, w*32+32) x all 64 cols (one head).
// x-tile hh: 0..15 q heads, 16..19 k heads, 20..23 v heads.
__global__ __launch_bounds__(256) void gemm_qkv(const __hip_bfloat16* __restrict__ A,
                                                const __hip_bfloat16* __restrict__ Bt,
                                                const int* __restrict__ positions,
                                                __hip_bfloat16* __restrict__ Qb,
                                                __hip_bfloat16* __restrict__ Kb,
                                                __hip_bfloat16* __restrict__ VtG) {
  const int K = H;
  long long m0 = (long long)blockIdx.y * 128;
  long long n0 = (long long)blockIdx.x * 64;

  __shared__ unsigned short As[2][128 * 64];
  __shared__ unsigned short Bs[2][64 * 64];

  int tid = threadIdx.x;
  int lane = tid & 63, w = tid >> 6;
  int qd = lane >> 4, ln16 = lane & 15;
  int l7 = ln16 & 7;

  floatx4 acc[2][4];
  floatx4 zero = {0.f, 0.f, 0.f, 0.f};
  #pragma unroll
  for (int i = 0; i < 2; i++)
    #pragma unroll
    for (int j = 0; j < 4; j++) acc[i][j] = zero;

  int rowA[4], kcA[4];
  const unsigned short* Arow[4];
  const unsigned short* Brow[2];
  #pragma unroll
  for (int it = 0; it < 4; it++) {
    int chunk = tid + it * 256;
    rowA[it] = chunk >> 3;
    kcA[it] = ((chunk & 7) ^ (rowA[it] & 7)) * 8;
    Arow[it] = (const unsigned short*)A + (m0 + rowA[it]) * K;
  }
  #pragma unroll
  for (int it = 0; it < 2; it++)
    Brow[it] = (const unsigned short*)Bt + (n0 + rowA[it]) * K;

  #pragma unroll
  for (int it = 0; it < 4; it++)
    gload16(Arow[it] + kcA[it], As[0] + (tid + it * 256) * 8);
  #pragma unroll
  for (int it = 0; it < 2; it++)
    gload16(Brow[it] + kcA[it], Bs[0] + (tid + it * 256) * 8);
  __syncthreads();

  int cur = 0;
  for (int k0 = 0; k0 < K; k0 += 64) {
    int kn = k0 + 64;
    if (kn < K) {
      #pragma unroll
      for (int it = 0; it < 4; it++)
        gload16(Arow[it] + kn + kcA[it], As[cur ^ 1] + (tid + it * 256) * 8);
      #pragma unroll
      for (int it = 0; it < 2; it++)
        gload16(Brow[it] + kn + kcA[it], Bs[cur ^ 1] + (tid + it * 256) * 8);
    }
    const unsigned short* Ac = As[cur];
    const unsigned short* Bc = Bs[cur];
    #pragma unroll
    for (int s = 0; s < 2; s++) {
      bf16x8 af[2], bfr[4];
      #pragma unroll
      for (int i = 0; i < 2; i++) {
        int row = w * 32 + i * 16 + ln16;
        af[i] = *(const bf16x8*)(Ac + row * 64 + (((s * 4 + qd) ^ l7) * 8));
      }
      #pragma unroll
      for (int j = 0; j < 4; j++) {
        int row = j * 16 + ln16;
        bfr[j] = *(const bf16x8*)(Bc + row * 64 + (((s * 4 + qd) ^ l7) * 8));
      }
      #pragma unroll
      for (int i = 0; i < 2; i++)
        #pragma unroll
        for (int j = 0; j < 4; j++)
          acc[i][j] = __builtin_amdgcn_mfma_f32_16x16x32_bf16(af[i], bfr[j], acc[i][j], 0, 0, 0);
    }
    __syncthreads();
    cur ^= 1;
  }

  int hh = blockIdx.x;
  if (hh < NH + NKV) {
    // q/k: RoPE pairs (d, d+32) = frags (j, j+2) in-thread; rmsnorm over 16-lane group
    bool isq = hh < NH;
    float invf0 = exp2f(-(float)ln16 * (18.93156857f / 32.0f));
    float invf1 = exp2f(-(float)(ln16 + 16) * (18.93156857f / 32.0f));
    #pragma unroll
    for (int i = 0; i < 2; i++) {
      #pragma unroll
      for (int r = 0; r < 4; r++) {
        int t = (int)m0 + w * 32 + i * 16 + qd * 4 + r;
        float pos = (float)positions[t];
        float c0, s0, c1, s1;
        __sincosf(pos * invf0, &s0, &c0);
        __sincosf(pos * invf1, &s1, &c1);
        float v0 = acc[i][0][r], v1 = acc[i][1][r], v2 = acc[i][2][r], v3 = acc[i][3][r];
        float ro0 = v0 * c0 - v2 * s0;
        float ro1 = v1 * c1 - v3 * s1;
        float ro2 = v2 * c0 + v0 * s0;
        float ro3 = v3 * c1 + v1 * s1;
        float sq = ro0 * ro0 + ro1 * ro1 + ro2 * ro2 + ro3 * ro3;
        sq += __shfl_xor(sq, 1, 64);
        sq += __shfl_xor(sq, 2, 64);
        sq += __shfl_xor(sq, 4, 64);
        sq += __shfl_xor(sq, 8, 64);
        float inv = rsqrtf(sq * (1.0f / (float)DH) + EPS);
        if (isq) inv *= (ATTN_SCALE * LOG2E);
        __hip_bfloat16* dst = isq ? (Qb + (size_t)t * (NH * DH) + hh * DH)
                                  : (Kb + (size_t)t * (NKV * DH) + (hh - NH) * DH);
        dst[0 * 16 + ln16] = __float2bfloat16(ro0 * inv);
        dst[1 * 16 + ln16] = __float2bfloat16(ro1 * inv);
        dst[2 * 16 + ln16] = __float2bfloat16(ro2 * inv);
        dst[3 * 16 + ln16] = __float2bfloat16(ro3 * inv);
      }
    }
  } else {
    // v: per-wave LDS transpose (reuse As scratch), then coalesced V^T write
    unsigned short* sw = ((unsigned short*)As) + w * 2560;  // 64 rows x 40 stride
    #pragma unroll
    for (int i = 0; i < 2; i++)
      #pragma unroll
      for (int j = 0; j < 4; j++)
        #pragma unroll
        for (int r = 0; r < 4; r++) {
          __hip_bfloat16 b = __float2bfloat16(acc[i][j][r]);
          sw[(j * 16 + ln16) * 40 + i * 16 + qd * 4 + r] = *(unsigned short*)&b;
        }
    int d = lane;
    int t0 = (int)m0 + w * 32;
    const unsigned short* sr = sw + d * 40;
    unsigned short* vd = (unsigned short*)VtG + (size_t)((hh - NH - NKV) * DH + d) * T + t0;
    #pragma unroll
    for (int kk = 0; kk < 4; kk++) {
      short tmp[8];
      #pragma unroll
      for (int q2 = 0; q2 < 8; q2++) tmp[q2] = sr[kk * 8 + q2];
      *(bf16x8*)(vd + kk * 8) = *(bf16x8*)tmp;
    }
  }
}

// ------- MFMA flash attention, KV-split + fused GQA group, 2-phase dbuf -------
// grid (T/64, NKV, ASPLIT); block = 4 waves, wave w owns head kvh*4+w (all 64 q rows).
// K/V staged once per tile; static-max softmax -> additive fp32 partials.
__global__ __launch_bounds__(256, 2) void attn_mfma(const __hip_bfloat16* __restrict__ Qb,
                                                    const __hip_bfloat16* __restrict__ Kbuf,
                                                    const __hip_bfloat16* __restrict__ VtG,
                                                    float* __restrict__ Opart,
                                                    float* __restrict__ Lpart) {
  int kvh = blockIdx.y;
  int qi = blockIdx.x;
  int sp = blockIdx.z;
  int q0 = qi * 64;
  int nt = qi + 1;  // causal KV tiles for this q-tile
  if (sp >= nt) return;

  __shared__ unsigned short Ks[2][64 * 64];
  __shared__ unsigned short Vs[2][64 * 64];
  __shared__ unsigned short Ps[4 * 16 * 64];

  int tid = threadIdx.x;
  int lane = tid & 63, w = tid >> 6;
  int h = kvh * 4 + w;
  int qd = lane >> 4, ln16 = lane & 15;
  int l7 = ln16 & 7;
  unsigned short* Pw = Ps + w * 16 * 64;

  int r0 = tid >> 3;
  int sc = ((tid & 7) ^ (r0 & 7)) * 8;

  const unsigned short* KbP = (const unsigned short*)Kbuf;
  const unsigned short* VtP = (const unsigned short*)VtG;

  // Q fragments: 4 row-tiles x 2 k-steps (per-wave head)
  bf16x8 aq[4][2];
  #pragma unroll
  for (int rt = 0; rt < 4; rt++) {
    const unsigned short* qp =
        (const unsigned short*)Qb + (size_t)(q0 + rt * 16 + ln16) * (NH * DH) + h * DH;
    aq[rt][0] = *(const bf16x8*)(qp + qd * 8);
    aq[rt][1] = *(const bf16x8*)(qp + 32 + qd * 8);
  }

  bf16x8 ones;
  #pragma unroll
  for (int i = 0; i < 8; i++) ones[i] = (short)0x3F80;  // bf16 1.0

  floatx4 O_[4][4], accl[4];
  floatx4 zero = {0.f, 0.f, 0.f, 0.f};
  #pragma unroll
  for (int rt = 0; rt < 4; rt++) {
    #pragma unroll
    for (int j = 0; j < 4; j++) O_[rt][j] = zero;
    accl[rt] = zero;
  }

  // prologue: stage tile kt=sp into buffer 0
  {
    int kb = sp * 64;
    gload16(KbP + (size_t)(kb + r0) * (NKV * DH) + kvh * DH + sc, Ks[0] + tid * 8);
    gload16(KbP + (size_t)(kb + r0 + 32) * (NKV * DH) + kvh * DH + sc, Ks[0] + tid * 8 + 2048);
    gload16(VtP + (size_t)(kvh * DH + r0) * T + kb + sc, Vs[0] + tid * 8);
    gload16(VtP + (size_t)(kvh * DH + r0 + 32) * T + kb + sc, Vs[0] + tid * 8 + 2048);
  }
  __syncthreads();

  int cur = 0;
  for (int kt = sp; kt < nt; kt += ASPLIT) {
    int ktn = kt + ASPLIT;
    if (ktn < nt) {
      int kb = ktn * 64;
      unsigned short* Kn = Ks[cur ^ 1];
      unsigned short* Vn = Vs[cur ^ 1];
      gload16(KbP + (size_t)(kb + r0) * (NKV * DH) + kvh * DH + sc, Kn + tid * 8);
      gload16(KbP + (size_t)(kb + r0 + 32) * (NKV * DH) + kvh * DH + sc, Kn + tid * 8 + 2048);
      gload16(VtP + (size_t)(kvh * DH + r0) * T + kb + sc, Vn + tid * 8);
      gload16(VtP + (size_t)(kvh * DH + r0 + 32) * T + kb + sc, Vn + tid * 8 + 2048);
    }
    const unsigned short* Kc = Ks[cur];
    const unsigned short* Vc = Vs[cur];
    int kb = kt * 64;

    #pragma unroll
    for (int rt = 0; rt < 4; rt++) {
      floatx4 S_[4];
      #pragma unroll
      for (int j = 0; j < 4; j++) S_[j] = zero;
      #pragma unroll
      for (int s = 0; s < 2; s++) {
        bf16x8 bk[4];
        #pragma unroll
        for (int j = 0; j < 4; j++)
          bk[j] = *(const bf16x8*)(Kc + (j * 16 + ln16) * 64 + (((s * 4 + qd) ^ l7) * 8));
        #pragma unroll
        for (int j = 0; j < 4; j++)
          S_[j] = __builtin_amdgcn_mfma_f32_16x16x32_bf16(aq[rt][s], bk[j], S_[j], 0, 0, 0);
      }

      int tq_base = q0 + rt * 16 + qd * 4;
      if (kb + 63 > q0 + rt * 16) {
        #pragma unroll
        for (int j = 0; j < 4; j++) {
          int tk = kb + j * 16 + ln16;
          #pragma unroll
          for (int r = 0; r < 4; r++)
            S_[j][r] = (tk <= tq_base + r) ? exp2f(S_[j][r] - MBOUND) : 0.f;
        }
      } else {
        #pragma unroll
        for (int j = 0; j < 4; j++)
          #pragma unroll
          for (int r = 0; r < 4; r++) S_[j][r] = exp2f(S_[j][r] - MBOUND);
      }

      #pragma unroll
      for (int j = 0; j < 4; j++)
        #pragma unroll
        for (int r = 0; r < 4; r++) {
          int row = qd * 4 + r;
          int pc = (((j * 2 + (ln16 >> 3)) ^ (row & 7)) * 8) + l7;
          __hip_bfloat16 pb = __float2bfloat16(S_[j][r]);
          Pw[row * 64 + pc] = *(unsigned short*)&pb;
        }

      #pragma unroll
      for (int s = 0; s < 2; s++) {
        bf16x8 ap = *(const bf16x8*)(Pw + ln16 * 64 + (((s * 4 + qd) ^ l7) * 8));
        bf16x8 bv[4];
        #pragma unroll
        for (int j = 0; j < 4; j++)
          bv[j] = *(const bf16x8*)(Vc + (j * 16 + ln16) * 64 + (((s * 4 + qd) ^ l7) * 8));
        #pragma unroll
        for (int j = 0; j < 4; j++)
          O_[rt][j] = __builtin_amdgcn_mfma_f32_16x16x32_bf16(ap, bv[j], O_[rt][j], 0, 0, 0);
        accl[rt] = __builtin_amdgcn_mfma_f32_16x16x32_bf16(ap, ones, accl[rt], 0, 0, 0);
      }
    }
    __syncthreads();
    cur ^= 1;
  }

  size_t pbase = ((size_t)(qi * NH + h) * ASPLIT + sp) * (64 * 64);
  #pragma unroll
  for (int rt = 0; rt < 4; rt++) {
    int rl_base = rt * 16 + qd * 4;
    #pragma unroll
    for (int j = 0; j < 4; j++)
      #pragma unroll
      for (int r = 0; r < 4; r++)
        Opart[pbase + (size_t)(rl_base + r) * 64 + j * 16 + ln16] = O_[rt][j][r];
  }
  if (ln16 == 0) {
    size_t lbase = ((size_t)(qi * NH + h) * ASPLIT + sp) * 64;
    #pragma unroll
    for (int rt = 0; rt < 4; rt++)
      #pragma unroll
      for (int r = 0; r < 4; r++) Lpart[lbase + rt * 16 + qd * 4 + r] = accl[rt][r];
  }
}

// ------- combine: ao = (sum_s Opart)/(sum_s Lpart); block(0,0) zeroes counts -------
__global__ __launch_bounds__(256) void attn_combine(const float* __restrict__ Opart,
                                                    const float* __restrict__ Lpart,
                                                    __hip_bfloat16* __restrict__ ao,
                                                    int* __restrict__ counts_g) {
  int qi = blockIdx.x, h = blockIdx.y;
  if (qi == 0 && h == 0 && threadIdx.x < 2 * NE) counts_g[threadIdx.x] = 0;
  int nv = (qi + 1 < ASPLIT) ? (qi + 1) : ASPLIT;
  int row = threadIdx.x >> 2;
  int c0 = (threadIdx.x & 3) * 16;
  size_t base = (size_t)(qi * NH + h) * ASPLIT * 4096;
  size_t lb = (size_t)(qi * NH + h) * ASPLIT * 64;
  float l = 0.f;
  float acc[16];
  #pragma unroll
  for (int i = 0; i < 16; i++) acc[i] = 0.f;
  for (int s = 0; s < nv; s++) {
    const float* Op = Opart + base + (size_t)s * 4096 + (size_t)row * 64 + c0;
    l += Lpart[lb + s * 64 + row];
    #pragma unroll
    for (int i = 0; i < 16; i += 4) {
      float4 v = *(const float4*)(Op + i);
      acc[i] += v.x; acc[i + 1] += v.y; acc[i + 2] += v.z; acc[i + 3] += v.w;
    }
  }
  float inv = 1.f / l;
  int t = qi * 64 + row;
  short ov[16];
  #pragma unroll
  for (int i = 0; i < 16; i++) {
    __hip_bfloat16 b = __float2bfloat16(acc[i] * inv);
    ov[i] = *(short*)&b;
  }
  short* dst = (short*)ao + (size_t)t * (NH * DH) + h * DH + c0;
  *(bf16x8*)dst = *(bf16x8*)&ov[0];
  *(bf16x8*)(dst + 8) = *(bf16x8*)&ov[8];
}

// ------- fused silu-mul over expert (gA2->gP) and shared (gS2->gPs), bf16x8 -------
__global__ __launch_bounds__(256) void silumul_both(const __hip_bfloat16* __restrict__ gA2,
                                                    const __hip_bfloat16* __restrict__ gS2,
                                                    __hip_bfloat16* __restrict__ gP,
                                                    __hip_bfloat16* __restrict__ gPs,
                                                    int n8each) {
  int i = blockIdx.x * blockDim.x + threadIdx.x;
  const __hip_bfloat16* src = gA2;
  __hip_bfloat16* dst = gP;
  if (i >= n8each) {
    i -= n8each;
    src = gS2;
    dst = gPs;
  }
  int el = i * 8;
  int row = el >> 10;
  int c = el & (FF - 1);
  const unsigned short* g = (const unsigned short*)src + (size_t)row * (2 * FF) + c;
  bf16x8 a8 = *(const bf16x8*)g;
  bf16x8 b8 = *(const bf16x8*)(g + FF);
  short o8[8];
  #pragma unroll
  for (int k = 0; k < 8; k++) {
    short sa = a8[k], sb = b8[k];
    float av = __bfloat162float(*(__hip_bfloat16*)&sa);
    float bv = __bfloat162float(*(__hip_bfloat16*)&sb);
    __hip_bfloat16 ob = __float2bfloat16(av / (1.f + __expf(-av)) * bv);
    o8[k] = *(short*)&ob;
  }
  *(bf16x8*)((unsigned short*)dst + el) = *(bf16x8*)o8;
}

// ------- single-block: scan counts -> offs, then assign perm/pos -------
__global__ __launch_bounds__(256) void assign_scan(const int* __restrict__ counts,
                                                   const int* __restrict__ idx,
                                                   int* __restrict__ offs,
                                                   int* __restrict__ cnt2,
                                                   int* __restrict__ perm,
                                                   int* __restrict__ pos) {
  __shared__ int offs_s[NE + 1];
  if (threadIdx.x == 0) {
    int s = 0;
    for (int e2 = 0; e2 < NE; e2++) { offs_s[e2] = s; offs[e2] = s; s += counts[e2]; }
    offs_s[NE] = s; offs[NE] = s;
  }
  __syncthreads();
  for (int t = threadIdx.x; t < T; t += 256) {
    int e2 = idx[t];
    int p = offs_s[e2] + atomicAdd(&cnt2[e2], 1);
    pos[t] = p;
    perm[p] = t;
  }
}

// ---------------- launcher ----------------
extern "C" void kernel_launch(void* const* d_in, const int* in_sizes, int n_in,
                              void* d_out, int out_size, void* d_ws, size_t ws_size,
                              hipStream_t stream) {
  const int* positions = (const int*)d_in[0];
  const float* hidden = (const float*)d_in[1];
  const float* ln1_w = (const float*)d_in[2];
  const float* ln2_w = (const float*)d_in[3];
  const float* wqkv = (const float*)d_in[4];
  const float* wo = (const float*)d_in[5];
  const float* router_w = (const float*)d_in[6];
  const float* w_gate = (const float*)d_in[7];
  const float* w_up = (const float*)d_in[8];
  const float* w_down = (const float*)d_in[9];
  const float* sh_gate = (const float*)d_in[10];
  const float* sh_up = (const float*)d_in[11];
  const float* sh_down = (const float*)d_in[12];

  float* out = (float*)d_out;
  float* resid = out + (size_t)T * H;

  char* p = (char*)d_ws;
  auto alloc = [&](size_t bytes) { char* r = p; p += (bytes + 255) & ~(size_t)255; return r; };

  float* qkv = (float*)alloc((size_t)T * QKVN * 4);  // Opart alias region only
  float* h2 = (float*)alloc((size_t)T * H * 4);      // dead (part of Opart region)
  float* gb1 = (float*)alloc((size_t)T * H * 4);     // aliased as gS2
  float* outp = (float*)alloc((size_t)T * H * 4);    // dead (part of Opart region)
  __hip_bfloat16* h1b = (__hip_bfloat16*)alloc((size_t)T * H * 2);  // later aliased as gPs
  __hip_bfloat16* aob = (__hip_bfloat16*)alloc((size_t)T * H * 2);
  __hip_bfloat16* h2b = (__hip_bfloat16*)alloc((size_t)T * H * 2);
  __hip_bfloat16* gA2 = (__hip_bfloat16*)alloc((size_t)T * 2 * FF * 2);
  __hip_bfloat16* gP = (__hip_bfloat16*)alloc((size_t)T * FF * 2);
  __hip_bfloat16* Qb = (__hip_bfloat16*)alloc((size_t)T * NH * DH * 2);
  __hip_bfloat16* Kb = (__hip_bfloat16*)alloc((size_t)T * NKV * DH * 2);
  __hip_bfloat16* VtG = (__hip_bfloat16*)alloc((size_t)NKV * DH * T * 2);
  __hip_bfloat16* wqkvT = (__hip_bfloat16*)alloc((size_t)H * QKVN * 2);
  __hip_bfloat16* woT = (__hip_bfloat16*)alloc((size_t)H * H * 2);
  __hip_bfloat16* wguT = (__hip_bfloat16*)alloc((size_t)9 * 2 * FF * H * 2);  // slot 8 = shared
  __hip_bfloat16* wdT = (__hip_bfloat16*)alloc((size_t)9 * H * FF * 2);       // slot 8 = shared
  int* counts = (int*)alloc(2 * NE * 4);
  int* cnt2 = counts + NE;
  int* offs = (int*)alloc((NE + 1) * 4);
  int* idx = (int*)alloc(T * 4);
  int* perm = (int*)alloc(T * 4);
  int* pos = (int*)alloc(T * 4);
  float* gate = (float*)alloc(T * 4);

  (void)h2; (void)outp; (void)pos;

  // dead-buffer aliases
  __hip_bfloat16* gS2 = (__hip_bfloat16*)gb1;   // T*2FF bf16 = T*H fp32 bytes
  __hip_bfloat16* gPs = h1b;                    // T*FF bf16 <= T*H bf16

  // attention split-K partials: alias over qkv..outp (all dead during attn window).
  float* Opart = qkv;
  float* Lpart = qkv + (size_t)(T / 64) * NH * ASPLIT * 4096;

  // weight transpose+cast (4 launches; gate+up merged, V^T fused into gemm_qkv)
  tcast9<<<dim3(QKVN / 64, H / 32, 1), 256, 0, stream>>>(wqkv, nullptr, nullptr, nullptr, wqkvT,
                                                         H, QKVN, QKVN, H, 0, 0, 0, 1);
  tcast9<<<dim3(H / 64, H / 32, 1), 256, 0, stream>>>(wo, nullptr, nullptr, nullptr, woT,
                                                      H, H, H, H, 0, 0, 0, 1);
  tcast9<<<dim3(FF / 64, H / 32, 18), 256, 0, stream>>>(w_gate, sh_gate, w_up, sh_up, wguT,
                                                        H, FF, FF, H, (long long)H * FF,
                                                        (long long)2 * H * FF, (long long)FF * H, 9);
  tcast9<<<dim3(H / 64, FF / 32, 9), 256, 0, stream>>>(w_down, sh_down, nullptr, nullptr, wdT,
                                                       FF, H, H, FF, (long long)FF * H,
                                                       (long long)H * FF, 0, 9);

  // 1. h1b = bf16(rmsnorm(hidden) * ln1_w)
  rmsnorm1024<<<T, 256, 0, stream>>>(hidden, ln1_w, h1b);
  // 2+3+4a. qkv GEMM with fused RoPE + q/k rmsnorm + V^T epilogue
  gemm_qkv<<<dim3(QKVN / 64, T / 128), 256, 0, stream>>>(h1b, wqkvT, positions, Qb, Kb, VtG);
  // 4b. attention (KV-split partials, 4 heads fused per block)
  attn_mfma<<<dim3(T / 64, NKV, ASPLIT), 256, 0, stream>>>(Qb, Kb, VtG, Opart, Lpart);
  // 4c. combine partials -> aob (+ zero counts for the router)
  attn_combine<<<dim3(T / 64, NH), 256, 0, stream>>>(Opart, Lpart, aob, counts);
  // 5+6. resid = ao @ wo + hidden (fused addend epilogue)
  gemm_bf16<<<dim3(H / 64, T / 128, 1), 256, 0, stream>>>(aob, nullptr, woT, resid, nullptr,
                                                          T, H, H, 0, nullptr, 0, nullptr, nullptr,
                                                          hidden, nullptr);
  // 7+8. h2b = bf16(rmsnorm(resid)*ln2_w); router top-1 + gate
  rms_router<<<T, 256, 0, stream>>>(resid, ln2_w, router_w, h2b, idx, gate, counts);
  // 9. scan + assign
  assign_scan<<<1, 256, 0, stream>>>(counts, idx, offs, cnt2, perm, pos);
  // 10. gate+up: experts (perm-gathered A + gate epilogue scale) + shared (z=8)
  gemm_bf16<<<dim3(2 * FF / 64, T / 128, 9), 256, 0, stream>>>(h2b, h2b, wguT, gA2, gS2,
                                                               T, 2 * FF, H, 1, offs,
                                                               (long long)2 * H * FF, perm, gate,
                                                               nullptr, nullptr);
  // 11. silu-mul both (bf16x8 vectorized)
  silumul_both<<<(2 * T * FF / 8) / 256, 256, 0, stream>>>(gA2, gS2, gP, gPs, T * FF / 8);
  // 12. down shared -> out (fp32, full write) ... must complete before expert scatter
  gemm_bf16<<<dim3(H / 64, T / 128, 1), 256, 0, stream>>>(gPs, nullptr, wdT + (size_t)8 * H * FF,
                                                          out, nullptr, T, H, FF, 0, nullptr, 0,
                                                          nullptr, nullptr, nullptr, nullptr);
  // 13. down experts: out[perm[gm]] += v (each token row owned by exactly one expert)
  gemm_bf16<<<dim3(H / 64, T / 128, 8), 256, 0, stream>>>(gP, nullptr, wdT, out, nullptr,
                                                          T, H, FF, 0, offs, (long long)FF * H,
                                                          nullptr, nullptr, nullptr, perm);
}

// Round 10
// 381.668 us; speedup vs baseline: 1.0798x; 1.0798x over previous
//
#include <hip/hip_runtime.h>
#include <hip/hip_bf16.h>
#include <cmath>
#include <cstdint>

#define T 2048
#define H 1024
#define NH 16
#define NKV 4
#define DH 64
#define NE 8
#define FF 1024
#define QKVN ((NH + 2 * NKV) * DH) /* 1536 */
#define EPS 1e-5f
#define ATTN_SCALE 0.125f
#define LOG2E 1.44269504f
#define MBOUND 12.0f  /* > 64*0.125*log2e = 11.54; scores can't exceed it (rms-normed q,k) */
#define ASPLIT 4      /* KV split factor: static-max softmax -> partials are additive */

typedef short bf16x8 __attribute__((ext_vector_type(8)));
typedef float floatx4 __attribute__((ext_vector_type(4)));

__device__ __forceinline__ void gload16(const void* g, void* l) {
  __builtin_amdgcn_global_load_lds((const __attribute__((address_space(1))) void*)g,
                                   (__attribute__((address_space(3))) void*)l, 16, 0, 0);
}

// ---------------- rmsnorm rows of 1024 -> bf16 ----------------
__global__ __launch_bounds__(256) void rmsnorm1024(const float* __restrict__ x,
                                                   const float* __restrict__ w,
                                                   __hip_bfloat16* __restrict__ yb) {
  int row = blockIdx.x;
  const float4* x4 = (const float4*)(x + (size_t)row * H);
  float4 v = x4[threadIdx.x];
  float s = v.x * v.x + v.y * v.y + v.z * v.z + v.w * v.w;
  #pragma unroll
  for (int o = 32; o; o >>= 1) s += __shfl_down(s, o, 64);
  __shared__ float red[4];
  if ((threadIdx.x & 63) == 0) red[threadIdx.x >> 6] = s;
  __syncthreads();
  s = red[0] + red[1] + red[2] + red[3];
  float inv = rsqrtf(s * (1.0f / (float)H) + EPS);
  float4 wv = ((const float4*)w)[threadIdx.x];
  __hip_bfloat16* yp = yb + (size_t)row * H + threadIdx.x * 4;
  yp[0] = __float2bfloat16(v.x * inv * wv.x);
  yp[1] = __float2bfloat16(v.y * inv * wv.y);
  yp[2] = __float2bfloat16(v.z * inv * wv.z);
  yp[3] = __float2bfloat16(v.w * inv * wv.w);
}

// -- fused: h2b = bf16(rmsnorm(resid)*w); router top-1 + sigmoid gate --
// (h2 fp32 buffer eliminated; counts zeroed earlier by attn_combine)
__global__ __launch_bounds__(256) void rms_router(const float* __restrict__ x,
                                                  const float* __restrict__ w,
                                                  const float* __restrict__ rw,
                                                  __hip_bfloat16* __restrict__ yb,
                                                  int* __restrict__ idx,
                                                  float* __restrict__ gate,
                                                  int* __restrict__ counts) {
  int row = blockIdx.x;
  float4 v = ((const float4*)(x + (size_t)row * H))[threadIdx.x];
  float s = v.x * v.x + v.y * v.y + v.z * v.z + v.w * v.w;
  #pragma unroll
  for (int o = 32; o; o >>= 1) s += __shfl_down(s, o, 64);
  __shared__ float red[4];
  if ((threadIdx.x & 63) == 0) red[threadIdx.x >> 6] = s;
  __syncthreads();
  s = red[0] + red[1] + red[2] + red[3];
  float inv = rsqrtf(s * (1.0f / (float)H) + EPS);
  float4 wv = ((const float4*)w)[threadIdx.x];
  float o0 = v.x * inv * wv.x, o1 = v.y * inv * wv.y, o2 = v.z * inv * wv.z, o3 = v.w * inv * wv.w;
  __hip_bfloat16* yp = yb + (size_t)row * H + threadIdx.x * 4;
  yp[0] = __float2bfloat16(o0);
  yp[1] = __float2bfloat16(o1);
  yp[2] = __float2bfloat16(o2);
  yp[3] = __float2bfloat16(o3);
  // router: this thread's 4 columns dot rw[c][e]
  const float* r0 = rw + (size_t)threadIdx.x * 4 * NE;
  float acc[NE];
  float4 a0 = *(const float4*)(r0 + 0), a1 = *(const float4*)(r0 + 4);
  float4 b0 = *(const float4*)(r0 + NE), b1 = *(const float4*)(r0 + NE + 4);
  float4 c0 = *(const float4*)(r0 + 2 * NE), c1 = *(const float4*)(r0 + 2 * NE + 4);
  float4 d0 = *(const float4*)(r0 + 3 * NE), d1 = *(const float4*)(r0 + 3 * NE + 4);
  acc[0] = o0 * a0.x + o1 * b0.x + o2 * c0.x + o3 * d0.x;
  acc[1] = o0 * a0.y + o1 * b0.y + o2 * c0.y + o3 * d0.y;
  acc[2] = o0 * a0.z + o1 * b0.z + o2 * c0.z + o3 * d0.z;
  acc[3] = o0 * a0.w + o1 * b0.w + o2 * c0.w + o3 * d0.w;
  acc[4] = o0 * a1.x + o1 * b1.x + o2 * c1.x + o3 * d1.x;
  acc[5] = o0 * a1.y + o1 * b1.y + o2 * c1.y + o3 * d1.y;
  acc[6] = o0 * a1.z + o1 * b1.z + o2 * c1.z + o3 * d1.z;
  acc[7] = o0 * a1.w + o1 * b1.w + o2 * c1.w + o3 * d1.w;
  #pragma unroll
  for (int off = 32; off; off >>= 1)
    #pragma unroll
    for (int e2 = 0; e2 < NE; e2++) acc[e2] += __shfl_down(acc[e2], off, 64);
  __shared__ float redr[4][NE];
  if ((threadIdx.x & 63) == 0)
    #pragma unroll
    for (int e2 = 0; e2 < NE; e2++) redr[threadIdx.x >> 6][e2] = acc[e2];
  __syncthreads();
  if (threadIdx.x == 0) {
    int best = 0;
    float bv = -3.4e38f;
    #pragma unroll
    for (int e2 = 0; e2 < NE; e2++) {
      float l = redr[0][e2] + redr[1][e2] + redr[2][e2] + redr[3][e2];
      if (l > bv) { bv = l; best = e2; }
    }
    idx[row] = best;
    gate[row] = 1.f / (1.f + expf(-bv));
    atomicAdd(&counts[best], 1);
  }
}

// -- fp32 [R][C] -> bf16 [C][R]; dual source-set batched (z<nz1: E/S, z>=nz1: E2/S2) --
__global__ __launch_bounds__(256) void tcast9(const float* __restrict__ srcE,
                                              const float* __restrict__ srcS,
                                              const float* __restrict__ srcE2,
                                              const float* __restrict__ srcS2,
                                              __hip_bfloat16* __restrict__ dst, int R, int C,
                                              long long srcStride, long long dstStride,
                                              long long sBatch, long long dBatch,
                                              long long d2Off, int nz1) {
  int z = blockIdx.z;
  const float* src;
  if (z < nz1) {
    src = (srcS && z == nz1 - 1) ? srcS : srcE + (long long)z * sBatch;
    dst += (long long)z * dBatch;
  } else {
    int z2 = z - nz1;
    src = (srcS2 && z2 == nz1 - 1) ? srcS2 : srcE2 + (long long)z2 * sBatch;
    dst += d2Off + (long long)z2 * dBatch;
  }
  int c0 = blockIdx.x * 64, r0 = blockIdx.y * 32;
  __shared__ float tile[32][65];
  int tid = threadIdx.x;
  int lr = tid >> 4;
  int lc = (tid & 15) * 4;
  #pragma unroll
  for (int it = 0; it < 2; it++) {
    float4 v = *(const float4*)(src + (long long)(r0 + lr + it * 16) * srcStride + c0 + lc);
    tile[lr + it * 16][lc + 0] = v.x;
    tile[lr + it * 16][lc + 1] = v.y;
    tile[lr + it * 16][lc + 2] = v.z;
    tile[lr + it * 16][lc + 3] = v.w;
  }
  __syncthreads();
  int oc = tid >> 2;
  int rr = (tid & 3) * 8;
  short ov[8];
  #pragma unroll
  for (int i = 0; i < 8; i++) {
    __hip_bfloat16 b = __float2bfloat16(tile[rr + i][oc]);
    ov[i] = *(short*)&b;
  }
  *(bf16x8*)((short*)dst + (long long)(c0 + oc) * dstStride + r0 + rr) = *(bf16x8*)ov;
}

// ------------- bf16 MFMA GEMM, 128x64 tile, BK=64, XOR-swizzled LDS -------------
// 2-phase: double-buffered LDS, prefetch next K-tile before computing current.
// C[M,N] = A[M,K] * Bt[N,K]^T ; last z slot (if A2) uses A2/full rows/Cout2.
// permA: row indirection for A (expert gather); gatev: epilogue row scale
// (linear domain); addC: optional fp32 addend added in epilogue.
__global__ __launch_bounds__(256) void gemm_bf16(const __hip_bfloat16* __restrict__ A,
                                                 const __hip_bfloat16* __restrict__ A2,
                                                 const __hip_bfloat16* __restrict__ Bt,
                                                 void* __restrict__ Cout, void* __restrict__ Cout2,
                                                 int M, int N, int K, int out_bf16,
                                                 const int* __restrict__ row_offs,
                                                 long long strideB,
                                                 const int* __restrict__ permA,
                                                 const float* __restrict__ gatev,
                                                 const float* __restrict__ addC) {
  int e = blockIdx.z;
  bool sh = (A2 != nullptr && e == (int)gridDim.z - 1);
  int rbeg = 0, rend = M;
  const __hip_bfloat16* Ap = A;
  void* Cp = Cout;
  const int* pA = permA;
  if (sh) {
    Ap = A2; Cp = Cout2; pA = nullptr;
  } else if (row_offs) {
    rbeg = row_offs[e]; rend = row_offs[e + 1];
  }
  long long m0 = rbeg + (long long)blockIdx.y * 128;
  if (m0 >= rend) return;
  long long n0 = (long long)blockIdx.x * 64;
  const __hip_bfloat16* Bp = Bt + (long long)e * strideB;

  __shared__ unsigned short As[2][128 * 64];
  __shared__ unsigned short Bs[2][64 * 64];

  int tid = threadIdx.x;
  int lane = tid & 63, w = tid >> 6;
  int wr = (w >> 1) * 64, wc = (w & 1) * 32;
  int qd = lane >> 4, ln16 = lane & 15;
  int l7 = ln16 & 7;

  floatx4 acc[4][2];
  floatx4 zero = {0.f, 0.f, 0.f, 0.f};
  #pragma unroll
  for (int i = 0; i < 4; i++)
    #pragma unroll
    for (int j = 0; j < 2; j++) acc[i][j] = zero;

  int rowA[4], kcA[4];
  const unsigned short* Arow[4];
  const unsigned short* Brow[2];
  #pragma unroll
  for (int it = 0; it < 4; it++) {
    int chunk = tid + it * 256;
    rowA[it] = chunk >> 3;
    kcA[it] = ((chunk & 7) ^ (rowA[it] & 7)) * 8;
    long long ra = m0 + rowA[it];
    if (ra >= rend) ra = rend - 1;
    long long tok = pA ? (long long)pA[ra] : ra;
    Arow[it] = (const unsigned short*)Ap + tok * K;
  }
  #pragma unroll
  for (int it = 0; it < 2; it++)
    Brow[it] = (const unsigned short*)Bp + (n0 + rowA[it]) * K;

  // prologue: stage k0=0 into buffer 0
  #pragma unroll
  for (int it = 0; it < 4; it++)
    gload16(Arow[it] + kcA[it], As[0] + (tid + it * 256) * 8);
  #pragma unroll
  for (int it = 0; it < 2; it++)
    gload16(Brow[it] + kcA[it], Bs[0] + (tid + it * 256) * 8);
  __syncthreads();

  int cur = 0;
  for (int k0 = 0; k0 < K; k0 += 64) {
    int kn = k0 + 64;
    if (kn < K) {
      #pragma unroll
      for (int it = 0; it < 4; it++)
        gload16(Arow[it] + kn + kcA[it], As[cur ^ 1] + (tid + it * 256) * 8);
      #pragma unroll
      for (int it = 0; it < 2; it++)
        gload16(Brow[it] + kn + kcA[it], Bs[cur ^ 1] + (tid + it * 256) * 8);
    }
    const unsigned short* Ac = As[cur];
    const unsigned short* Bc = Bs[cur];
    #pragma unroll
    for (int s = 0; s < 2; s++) {
      bf16x8 af[4], bfr[2];
      #pragma unroll
      for (int i = 0; i < 4; i++) {
        int row = wr + i * 16 + ln16;
        af[i] = *(const bf16x8*)(Ac + row * 64 + (((s * 4 + qd) ^ l7) * 8));
      }
      #pragma unroll
      for (int j = 0; j < 2; j++) {
        int row = wc + j * 16 + ln16;
        bfr[j] = *(const bf16x8*)(Bc + row * 64 + (((s * 4 + qd) ^ l7) * 8));
      }
      #pragma unroll
      for (int i = 0; i < 4; i++)
        #pragma unroll
        for (int j = 0; j < 2; j++)
          acc[i][j] = __builtin_amdgcn_mfma_f32_16x16x32_bf16(af[i], bfr[j], acc[i][j], 0, 0, 0);
    }
    __syncthreads();
    cur ^= 1;
  }

  #pragma unroll
  for (int i = 0; i < 4; i++) {
    #pragma unroll
    for (int r = 0; r < 4; r++) {
      long long gm = m0 + wr + i * 16 + qd * 4 + r;
      if (gm < rend) {
        float gsc = 1.0f;
        if (pA && gatev) gsc = gatev[pA[gm]];
        #pragma unroll
        for (int j = 0; j < 2; j++) {
          long long gn = n0 + wc + j * 16 + ln16;
          float v = acc[i][j][r] * gsc;
          if (addC) v += addC[gm * N + gn];
          if (out_bf16)
            ((__hip_bfloat16*)Cp)[gm * N + gn] = __float2bfloat16(v);
          else
            ((float*)Cp)[gm * N + gn] = v;
        }
      }
    }
  }
}

// ---- specialized qkv GEMM: fused RoPE + per-head rmsnorm + Qb/Kb/V^T epilogue ----
// grid (QKVN/64 = 24, T/128). Wave w owns rows [w*32, w*32+32) x all 64 cols (one head).
// x-tile hh: 0..15 q heads, 16..19 k heads, 20..23 v heads.
__global__ __launch_bounds__(256) void gemm_qkv(const __hip_bfloat16* __restrict__ A,
                                                const __hip_bfloat16* __restrict__ Bt,
                                                const int* __restrict__ positions,
                                                __hip_bfloat16* __restrict__ Qb,
                                                __hip_bfloat16* __restrict__ Kb,
                                                __hip_bfloat16* __restrict__ VtG) {
  const int K = H;
  long long m0 = (long long)blockIdx.y * 128;
  long long n0 = (long long)blockIdx.x * 64;

  __shared__ unsigned short As[2][128 * 64];
  __shared__ unsigned short Bs[2][64 * 64];

  int tid = threadIdx.x;
  int lane = tid & 63, w = tid >> 6;
  int qd = lane >> 4, ln16 = lane & 15;
  int l7 = ln16 & 7;

  floatx4 acc[2][4];
  floatx4 zero = {0.f, 0.f, 0.f, 0.f};
  #pragma unroll
  for (int i = 0; i < 2; i++)
    #pragma unroll
    for (int j = 0; j < 4; j++) acc[i][j] = zero;

  int rowA[4], kcA[4];
  const unsigned short* Arow[4];
  const unsigned short* Brow[2];
  #pragma unroll
  for (int it = 0; it < 4; it++) {
    int chunk = tid + it * 256;
    rowA[it] = chunk >> 3;
    kcA[it] = ((chunk & 7) ^ (rowA[it] & 7)) * 8;
    Arow[it] = (const unsigned short*)A + (m0 + rowA[it]) * K;
  }
  #pragma unroll
  for (int it = 0; it < 2; it++)
    Brow[it] = (const unsigned short*)Bt + (n0 + rowA[it]) * K;

  #pragma unroll
  for (int it = 0; it < 4; it++)
    gload16(Arow[it] + kcA[it], As[0] + (tid + it * 256) * 8);
  #pragma unroll
  for (int it = 0; it < 2; it++)
    gload16(Brow[it] + kcA[it], Bs[0] + (tid + it * 256) * 8);
  __syncthreads();

  int cur = 0;
  for (int k0 = 0; k0 < K; k0 += 64) {
    int kn = k0 + 64;
    if (kn < K) {
      #pragma unroll
      for (int it = 0; it < 4; it++)
        gload16(Arow[it] + kn + kcA[it], As[cur ^ 1] + (tid + it * 256) * 8);
      #pragma unroll
      for (int it = 0; it < 2; it++)
        gload16(Brow[it] + kn + kcA[it], Bs[cur ^ 1] + (tid + it * 256) * 8);
    }
    const unsigned short* Ac = As[cur];
    const unsigned short* Bc = Bs[cur];
    #pragma unroll
    for (int s = 0; s < 2; s++) {
      bf16x8 af[2], bfr[4];
      #pragma unroll
      for (int i = 0; i < 2; i++) {
        int row = w * 32 + i * 16 + ln16;
        af[i] = *(const bf16x8*)(Ac + row * 64 + (((s * 4 + qd) ^ l7) * 8));
      }
      #pragma unroll
      for (int j = 0; j < 4; j++) {
        int row = j * 16 + ln16;
        bfr[j] = *(const bf16x8*)(Bc + row * 64 + (((s * 4 + qd) ^ l7) * 8));
      }
      #pragma unroll
      for (int i = 0; i < 2; i++)
        #pragma unroll
        for (int j = 0; j < 4; j++)
          acc[i][j] = __builtin_amdgcn_mfma_f32_16x16x32_bf16(af[i], bfr[j], acc[i][j], 0, 0, 0);
    }
    __syncthreads();
    cur ^= 1;
  }

  int hh = blockIdx.x;
  if (hh < NH + NKV) {
    // q/k: RoPE pairs (d, d+32) = frags (j, j+2) in-thread; rmsnorm over 16-lane group
    bool isq = hh < NH;
    float invf0 = exp2f(-(float)ln16 * (18.93156857f / 32.0f));
    float invf1 = exp2f(-(float)(ln16 + 16) * (18.93156857f / 32.0f));
    #pragma unroll
    for (int i = 0; i < 2; i++) {
      #pragma unroll
      for (int r = 0; r < 4; r++) {
        int t = (int)m0 + w * 32 + i * 16 + qd * 4 + r;
        float pos = (float)positions[t];
        float c0, s0, c1, s1;
        __sincosf(pos * invf0, &s0, &c0);
        __sincosf(pos * invf1, &s1, &c1);
        float v0 = acc[i][0][r], v1 = acc[i][1][r], v2 = acc[i][2][r], v3 = acc[i][3][r];
        float ro0 = v0 * c0 - v2 * s0;
        float ro1 = v1 * c1 - v3 * s1;
        float ro2 = v2 * c0 + v0 * s0;
        float ro3 = v3 * c1 + v1 * s1;
        float sq = ro0 * ro0 + ro1 * ro1 + ro2 * ro2 + ro3 * ro3;
        sq += __shfl_xor(sq, 1, 64);
        sq += __shfl_xor(sq, 2, 64);
        sq += __shfl_xor(sq, 4, 64);
        sq += __shfl_xor(sq, 8, 64);
        float inv = rsqrtf(sq * (1.0f / (float)DH) + EPS);
        if (isq) inv *= (ATTN_SCALE * LOG2E);
        __hip_bfloat16* dst = isq ? (Qb + (size_t)t * (NH * DH) + hh * DH)
                                  : (Kb + (size_t)t * (NKV * DH) + (hh - NH) * DH);
        dst[0 * 16 + ln16] = __float2bfloat16(ro0 * inv);
        dst[1 * 16 + ln16] = __float2bfloat16(ro1 * inv);
        dst[2 * 16 + ln16] = __float2bfloat16(ro2 * inv);
        dst[3 * 16 + ln16] = __float2bfloat16(ro3 * inv);
      }
    }
  } else {
    // v: per-wave LDS transpose (reuse As scratch), then coalesced V^T write
    unsigned short* sw = ((unsigned short*)As) + w * 2560;  // 64 rows x 40 stride
    #pragma unroll
    for (int i = 0; i < 2; i++)
      #pragma unroll
      for (int j = 0; j < 4; j++)
        #pragma unroll
        for (int r = 0; r < 4; r++) {
          __hip_bfloat16 b = __float2bfloat16(acc[i][j][r]);
          sw[(j * 16 + ln16) * 40 + i * 16 + qd * 4 + r] = *(unsigned short*)&b;
        }
    int d = lane;
    int t0 = (int)m0 + w * 32;
    const unsigned short* sr = sw + d * 40;
    unsigned short* vd = (unsigned short*)VtG + (size_t)((hh - NH - NKV) * DH + d) * T + t0;
    #pragma unroll
    for (int kk = 0; kk < 4; kk++) {
      short tmp[8];
      #pragma unroll
      for (int q2 = 0; q2 < 8; q2++) tmp[q2] = sr[kk * 8 + q2];
      *(bf16x8*)(vd + kk * 8) = *(bf16x8*)tmp;
    }
  }
}

// ------- MFMA flash attention, KV-split + fused GQA group, 2-phase dbuf -------
// grid (T/64, NKV, ASPLIT); block = 4 waves, wave w owns head kvh*4+w (all 64 q rows).
// K/V staged once per tile; static-max softmax -> additive fp32 partials.
__global__ __launch_bounds__(256, 2) void attn_mfma(const __hip_bfloat16* __restrict__ Qb,
                                                    const __hip_bfloat16* __restrict__ Kbuf,
                                                    const __hip_bfloat16* __restrict__ VtG,
                                                    float* __restrict__ Opart,
                                                    float* __restrict__ Lpart) {
  int kvh = blockIdx.y;
  int qi = blockIdx.x;
  int sp = blockIdx.z;
  int q0 = qi * 64;
  int nt = qi + 1;  // causal KV tiles for this q-tile
  if (sp >= nt) return;

  __shared__ unsigned short Ks[2][64 * 64];
  __shared__ unsigned short Vs[2][64 * 64];
  __shared__ unsigned short Ps[4 * 16 * 64];

  int tid = threadIdx.x;
  int lane = tid & 63, w = tid >> 6;
  int h = kvh * 4 + w;
  int qd = lane >> 4, ln16 = lane & 15;
  int l7 = ln16 & 7;
  unsigned short* Pw = Ps + w * 16 * 64;

  int r0 = tid >> 3;
  int sc = ((tid & 7) ^ (r0 & 7)) * 8;

  const unsigned short* KbP = (const unsigned short*)Kbuf;
  const unsigned short* VtP = (const unsigned short*)VtG;

  // Q fragments: 4 row-tiles x 2 k-steps (per-wave head)
  bf16x8 aq[4][2];
  #pragma unroll
  for (int rt = 0; rt < 4; rt++) {
    const unsigned short* qp =
        (const unsigned short*)Qb + (size_t)(q0 + rt * 16 + ln16) * (NH * DH) + h * DH;
    aq[rt][0] = *(const bf16x8*)(qp + qd * 8);
    aq[rt][1] = *(const bf16x8*)(qp + 32 + qd * 8);
  }

  bf16x8 ones;
  #pragma unroll
  for (int i = 0; i < 8; i++) ones[i] = (short)0x3F80;  // bf16 1.0

  floatx4 O_[4][4], accl[4];
  floatx4 zero = {0.f, 0.f, 0.f, 0.f};
  #pragma unroll
  for (int rt = 0; rt < 4; rt++) {
    #pragma unroll
    for (int j = 0; j < 4; j++) O_[rt][j] = zero;
    accl[rt] = zero;
  }

  // prologue: stage tile kt=sp into buffer 0
  {
    int kb = sp * 64;
    gload16(KbP + (size_t)(kb + r0) * (NKV * DH) + kvh * DH + sc, Ks[0] + tid * 8);
    gload16(KbP + (size_t)(kb + r0 + 32) * (NKV * DH) + kvh * DH + sc, Ks[0] + tid * 8 + 2048);
    gload16(VtP + (size_t)(kvh * DH + r0) * T + kb + sc, Vs[0] + tid * 8);
    gload16(VtP + (size_t)(kvh * DH + r0 + 32) * T + kb + sc, Vs[0] + tid * 8 + 2048);
  }
  __syncthreads();

  int cur = 0;
  for (int kt = sp; kt < nt; kt += ASPLIT) {
    int ktn = kt + ASPLIT;
    if (ktn < nt) {
      int kb = ktn * 64;
      unsigned short* Kn = Ks[cur ^ 1];
      unsigned short* Vn = Vs[cur ^ 1];
      gload16(KbP + (size_t)(kb + r0) * (NKV * DH) + kvh * DH + sc, Kn + tid * 8);
      gload16(KbP + (size_t)(kb + r0 + 32) * (NKV * DH) + kvh * DH + sc, Kn + tid * 8 + 2048);
      gload16(VtP + (size_t)(kvh * DH + r0) * T + kb + sc, Vn + tid * 8);
      gload16(VtP + (size_t)(kvh * DH + r0 + 32) * T + kb + sc, Vn + tid * 8 + 2048);
    }
    const unsigned short* Kc = Ks[cur];
    const unsigned short* Vc = Vs[cur];
    int kb = kt * 64;

    #pragma unroll
    for (int rt = 0; rt < 4; rt++) {
      floatx4 S_[4];
      #pragma unroll
      for (int j = 0; j < 4; j++) S_[j] = zero;
      #pragma unroll
      for (int s = 0; s < 2; s++) {
        bf16x8 bk[4];
        #pragma unroll
        for (int j = 0; j < 4; j++)
          bk[j] = *(const bf16x8*)(Kc + (j * 16 + ln16) * 64 + (((s * 4 + qd) ^ l7) * 8));
        #pragma unroll
        for (int j = 0; j < 4; j++)
          S_[j] = __builtin_amdgcn_mfma_f32_16x16x32_bf16(aq[rt][s], bk[j], S_[j], 0, 0, 0);
      }

      int tq_base = q0 + rt * 16 + qd * 4;
      if (kb + 63 > q0 + rt * 16) {
        #pragma unroll
        for (int j = 0; j < 4; j++) {
          int tk = kb + j * 16 + ln16;
          #pragma unroll
          for (int r = 0; r < 4; r++)
            S_[j][r] = (tk <= tq_base + r) ? exp2f(S_[j][r] - MBOUND) : 0.f;
        }
      } else {
        #pragma unroll
        for (int j = 0; j < 4; j++)
          #pragma unroll
          for (int r = 0; r < 4; r++) S_[j][r] = exp2f(S_[j][r] - MBOUND);
      }

      #pragma unroll
      for (int j = 0; j < 4; j++)
        #pragma unroll
        for (int r = 0; r < 4; r++) {
          int row = qd * 4 + r;
          int pc = (((j * 2 + (ln16 >> 3)) ^ (row & 7)) * 8) + l7;
          __hip_bfloat16 pb = __float2bfloat16(S_[j][r]);
          Pw[row * 64 + pc] = *(unsigned short*)&pb;
        }

      #pragma unroll
      for (int s = 0; s < 2; s++) {
        bf16x8 ap = *(const bf16x8*)(Pw + ln16 * 64 + (((s * 4 + qd) ^ l7) * 8));
        bf16x8 bv[4];
        #pragma unroll
        for (int j = 0; j < 4; j++)
          bv[j] = *(const bf16x8*)(Vc + (j * 16 + ln16) * 64 + (((s * 4 + qd) ^ l7) * 8));
        #pragma unroll
        for (int j = 0; j < 4; j++)
          O_[rt][j] = __builtin_amdgcn_mfma_f32_16x16x32_bf16(ap, bv[j], O_[rt][j], 0, 0, 0);
        accl[rt] = __builtin_amdgcn_mfma_f32_16x16x32_bf16(ap, ones, accl[rt], 0, 0, 0);
      }
    }
    __syncthreads();
    cur ^= 1;
  }

  size_t pbase = ((size_t)(qi * NH + h) * ASPLIT + sp) * (64 * 64);
  #pragma unroll
  for (int rt = 0; rt < 4; rt++) {
    int rl_base = rt * 16 + qd * 4;
    #pragma unroll
    for (int j = 0; j < 4; j++)
      #pragma unroll
      for (int r = 0; r < 4; r++)
        Opart[pbase + (size_t)(rl_base + r) * 64 + j * 16 + ln16] = O_[rt][j][r];
  }
  if (ln16 == 0) {
    size_t lbase = ((size_t)(qi * NH + h) * ASPLIT + sp) * 64;
    #pragma unroll
    for (int rt = 0; rt < 4; rt++)
      #pragma unroll
      for (int r = 0; r < 4; r++) Lpart[lbase + rt * 16 + qd * 4 + r] = accl[rt][r];
  }
}

// ------- combine: ao = (sum_s Opart)/(sum_s Lpart); block(0,0) zeroes counts -------
__global__ __launch_bounds__(256) void attn_combine(const float* __restrict__ Opart,
                                                    const float* __restrict__ Lpart,
                                                    __hip_bfloat16* __restrict__ ao,
                                                    int* __restrict__ counts_g) {
  int qi = blockIdx.x, h = blockIdx.y;
  if (qi == 0 && h == 0 && threadIdx.x < 2 * NE) counts_g[threadIdx.x] = 0;
  int nv = (qi + 1 < ASPLIT) ? (qi + 1) : ASPLIT;
  int row = threadIdx.x >> 2;
  int c0 = (threadIdx.x & 3) * 16;
  size_t base = (size_t)(qi * NH + h) * ASPLIT * 4096;
  size_t lb = (size_t)(qi * NH + h) * ASPLIT * 64;
  float l = 0.f;
  float acc[16];
  #pragma unroll
  for (int i = 0; i < 16; i++) acc[i] = 0.f;
  for (int s = 0; s < nv; s++) {
    const float* Op = Opart + base + (size_t)s * 4096 + (size_t)row * 64 + c0;
    l += Lpart[lb + s * 64 + row];
    #pragma unroll
    for (int i = 0; i < 16; i += 4) {
      float4 v = *(const float4*)(Op + i);
      acc[i] += v.x; acc[i + 1] += v.y; acc[i + 2] += v.z; acc[i + 3] += v.w;
    }
  }
  float inv = 1.f / l;
  int t = qi * 64 + row;
  short ov[16];
  #pragma unroll
  for (int i = 0; i < 16; i++) {
    __hip_bfloat16 b = __float2bfloat16(acc[i] * inv);
    ov[i] = *(short*)&b;
  }
  short* dst = (short*)ao + (size_t)t * (NH * DH) + h * DH + c0;
  *(bf16x8*)dst = *(bf16x8*)&ov[0];
  *(bf16x8*)(dst + 8) = *(bf16x8*)&ov[8];
}

// ------- fused silu-mul over expert (gA2->gP) and shared (gS2->gPs), bf16x8 -------
__global__ __launch_bounds__(256) void silumul_both(const __hip_bfloat16* __restrict__ gA2,
                                                    const __hip_bfloat16* __restrict__ gS2,
                                                    __hip_bfloat16* __restrict__ gP,
                                                    __hip_bfloat16* __restrict__ gPs,
                                                    int n8each) {
  int i = blockIdx.x * blockDim.x + threadIdx.x;
  const __hip_bfloat16* src = gA2;
  __hip_bfloat16* dst = gP;
  if (i >= n8each) {
    i -= n8each;
    src = gS2;
    dst = gPs;
  }
  int el = i * 8;
  int row = el >> 10;
  int c = el & (FF - 1);
  const unsigned short* g = (const unsigned short*)src + (size_t)row * (2 * FF) + c;
  bf16x8 a8 = *(const bf16x8*)g;
  bf16x8 b8 = *(const bf16x8*)(g + FF);
  short o8[8];
  #pragma unroll
  for (int k = 0; k < 8; k++) {
    short sa = a8[k], sb = b8[k];
    float av = __bfloat162float(*(__hip_bfloat16*)&sa);
    float bv = __bfloat162float(*(__hip_bfloat16*)&sb);
    __hip_bfloat16 ob = __float2bfloat16(av / (1.f + __expf(-av)) * bv);
    o8[k] = *(short*)&ob;
  }
  *(bf16x8*)((unsigned short*)dst + el) = *(bf16x8*)o8;
}

// ------- single-block: scan counts -> offs, then assign perm/pos -------
__global__ __launch_bounds__(256) void assign_scan(const int* __restrict__ counts,
                                                   const int* __restrict__ idx,
                                                   int* __restrict__ offs,
                                                   int* __restrict__ cnt2,
                                                   int* __restrict__ perm,
                                                   int* __restrict__ pos) {
  __shared__ int offs_s[NE + 1];
  if (threadIdx.x == 0) {
    int s = 0;
    for (int e2 = 0; e2 < NE; e2++) { offs_s[e2] = s; offs[e2] = s; s += counts[e2]; }
    offs_s[NE] = s; offs[NE] = s;
  }
  __syncthreads();
  for (int t = threadIdx.x; t < T; t += 256) {
    int e2 = idx[t];
    int p = offs_s[e2] + atomicAdd(&cnt2[e2], 1);
    pos[t] = p;
    perm[p] = t;
  }
}

__global__ __launch_bounds__(256) void final_add_kernel(float* __restrict__ out,
                                                        const float* __restrict__ outp,
                                                        const int* __restrict__ pos) {
  int t = blockIdx.x;
  int p = pos[t];
  const float4* src = (const float4*)(outp + (long long)p * H);
  float4* dst = (float4*)(out + (long long)t * H);
  float4 a = dst[threadIdx.x];
  float4 b = src[threadIdx.x];
  a.x += b.x; a.y += b.y; a.z += b.z; a.w += b.w;
  dst[threadIdx.x] = a;
}

// ---------------- launcher ----------------
extern "C" void kernel_launch(void* const* d_in, const int* in_sizes, int n_in,
                              void* d_out, int out_size, void* d_ws, size_t ws_size,
                              hipStream_t stream) {
  const int* positions = (const int*)d_in[0];
  const float* hidden = (const float*)d_in[1];
  const float* ln1_w = (const float*)d_in[2];
  const float* ln2_w = (const float*)d_in[3];
  const float* wqkv = (const float*)d_in[4];
  const float* wo = (const float*)d_in[5];
  const float* router_w = (const float*)d_in[6];
  const float* w_gate = (const float*)d_in[7];
  const float* w_up = (const float*)d_in[8];
  const float* w_down = (const float*)d_in[9];
  const float* sh_gate = (const float*)d_in[10];
  const float* sh_up = (const float*)d_in[11];
  const float* sh_down = (const float*)d_in[12];

  float* out = (float*)d_out;
  float* resid = out + (size_t)T * H;

  char* p = (char*)d_ws;
  auto alloc = [&](size_t bytes) { char* r = p; p += (bytes + 255) & ~(size_t)255; return r; };

  float* qkv = (float*)alloc((size_t)T * QKVN * 4);  // Opart alias region only
  float* h2 = (float*)alloc((size_t)T * H * 4);      // dead (part of Opart region)
  float* gb1 = (float*)alloc((size_t)T * H * 4);     // aliased as gS2
  float* outp = (float*)alloc((size_t)T * H * 4);    // expert down output (permuted rows)
  __hip_bfloat16* h1b = (__hip_bfloat16*)alloc((size_t)T * H * 2);  // later aliased as gPs
  __hip_bfloat16* aob = (__hip_bfloat16*)alloc((size_t)T * H * 2);
  __hip_bfloat16* h2b = (__hip_bfloat16*)alloc((size_t)T * H * 2);
  __hip_bfloat16* gA2 = (__hip_bfloat16*)alloc((size_t)T * 2 * FF * 2);
  __hip_bfloat16* gP = (__hip_bfloat16*)alloc((size_t)T * FF * 2);
  __hip_bfloat16* Qb = (__hip_bfloat16*)alloc((size_t)T * NH * DH * 2);
  __hip_bfloat16* Kb = (__hip_bfloat16*)alloc((size_t)T * NKV * DH * 2);
  __hip_bfloat16* VtG = (__hip_bfloat16*)alloc((size_t)NKV * DH * T * 2);
  __hip_bfloat16* wqkvT = (__hip_bfloat16*)alloc((size_t)H * QKVN * 2);
  __hip_bfloat16* woT = (__hip_bfloat16*)alloc((size_t)H * H * 2);
  __hip_bfloat16* wguT = (__hip_bfloat16*)alloc((size_t)9 * 2 * FF * H * 2);  // slot 8 = shared
  __hip_bfloat16* wdT = (__hip_bfloat16*)alloc((size_t)9 * H * FF * 2);       // slot 8 = shared
  int* counts = (int*)alloc(2 * NE * 4);
  int* cnt2 = counts + NE;
  int* offs = (int*)alloc((NE + 1) * 4);
  int* idx = (int*)alloc(T * 4);
  int* perm = (int*)alloc(T * 4);
  int* pos = (int*)alloc(T * 4);
  float* gate = (float*)alloc(T * 4);

  (void)h2;

  // dead-buffer aliases
  __hip_bfloat16* gS2 = (__hip_bfloat16*)gb1;   // T*2FF bf16 = T*H fp32 bytes
  __hip_bfloat16* gPs = h1b;                    // T*FF bf16 <= T*H bf16

  // attention split-K partials: alias over qkv..outp (all dead during attn window).
  float* Opart = qkv;
  float* Lpart = qkv + (size_t)(T / 64) * NH * ASPLIT * 4096;

  // weight transpose+cast (4 launches; gate+up merged, V^T fused into gemm_qkv)
  tcast9<<<dim3(QKVN / 64, H / 32, 1), 256, 0, stream>>>(wqkv, nullptr, nullptr, nullptr, wqkvT,
                                                         H, QKVN, QKVN, H, 0, 0, 0, 1);
  tcast9<<<dim3(H / 64, H / 32, 1), 256, 0, stream>>>(wo, nullptr, nullptr, nullptr, woT,
                                                      H, H, H, H, 0, 0, 0, 1);
  tcast9<<<dim3(FF / 64, H / 32, 18), 256, 0, stream>>>(w_gate, sh_gate, w_up, sh_up, wguT,
                                                        H, FF, FF, H, (long long)H * FF,
                                                        (long long)2 * H * FF, (long long)FF * H, 9);
  tcast9<<<dim3(H / 64, FF / 32, 9), 256, 0, stream>>>(w_down, sh_down, nullptr, nullptr, wdT,
                                                       FF, H, H, FF, (long long)FF * H,
                                                       (long long)H * FF, 0, 9);

  // 1. h1b = bf16(rmsnorm(hidden) * ln1_w)
  rmsnorm1024<<<T, 256, 0, stream>>>(hidden, ln1_w, h1b);
  // 2+3+4a. qkv GEMM with fused RoPE + q/k rmsnorm + V^T epilogue
  gemm_qkv<<<dim3(QKVN / 64, T / 128), 256, 0, stream>>>(h1b, wqkvT, positions, Qb, Kb, VtG);
  // 4b. attention (KV-split partials, 4 heads fused per block)
  attn_mfma<<<dim3(T / 64, NKV, ASPLIT), 256, 0, stream>>>(Qb, Kb, VtG, Opart, Lpart);
  // 4c. combine partials -> aob (+ zero counts for the router)
  attn_combine<<<dim3(T / 64, NH), 256, 0, stream>>>(Opart, Lpart, aob, counts);
  // 5+6. resid = ao @ wo + hidden (fused addend epilogue)
  gemm_bf16<<<dim3(H / 64, T / 128, 1), 256, 0, stream>>>(aob, nullptr, woT, resid, nullptr,
                                                          T, H, H, 0, nullptr, 0, nullptr, nullptr,
                                                          hidden);
  // 7+8. h2b = bf16(rmsnorm(resid)*ln2_w); router top-1 + gate
  rms_router<<<T, 256, 0, stream>>>(resid, ln2_w, router_w, h2b, idx, gate, counts);
  // 9. scan + assign
  assign_scan<<<1, 256, 0, stream>>>(counts, idx, offs, cnt2, perm, pos);
  // 10. gate+up: experts (perm-gathered A + gate epilogue scale) + shared (z=8)
  gemm_bf16<<<dim3(2 * FF / 64, T / 128, 9), 256, 0, stream>>>(h2b, h2b, wguT, gA2, gS2,
                                                               T, 2 * FF, H, 1, offs,
                                                               (long long)2 * H * FF, perm, gate,
                                                               nullptr);
  // 11. silu-mul both (bf16x8 vectorized)
  silumul_both<<<(2 * T * FF / 8) / 256, 256, 0, stream>>>(gA2, gS2, gP, gPs, T * FF / 8);
  // 12. down: experts -> outp (fp32, permuted rows), shared -> out (fp32), one z=9 launch
  gemm_bf16<<<dim3(H / 64, T / 128, 9), 256, 0, stream>>>(gP, gPs, wdT, outp, out,
                                                          T, H, FF, 0, offs, (long long)FF * H,
                                                          nullptr, nullptr, nullptr);
  // 13. out += routed (un-permute via pos)
  final_add_kernel<<<T, 256, 0, stream>>>(out, outp, pos);
}